// Round 17
// baseline (130.599 us; speedup 1.0000x reference)
//
#include <hip/hip_runtime.h>
#include <math.h>

#define NN 100000
#define NE 1600000
#define D 128

#define NB 782                          // buckets of 128 dst-nodes
#define CAPB 2560                       // fixed ebuf capacity per bucket
#define CURSTRIDE 16                    // cursor padded to one 64B line per bucket
#define SC_BLOCKS 512                   // scatter role blocks
#define SC_CHUNK 3125                   // 512 x 3125 = 1.6M exactly
#define SC_IT 13                        // ceil(3125/256)
#define CAP 768                         // pull sorted tile (quarter-bucket, mean 512, +11 sigma)

#define BM 64                           // rows per gemm block
#define GM_BLOCKS 1563                  // ceil(NN/64)
#define GRID (SC_BLOCKS + GM_BLOCKS)    // 2075
#define TPAD 264                        // transpose-epilogue row stride (bytes)

#define ASG __attribute__((address_space(1)))
#define ASL __attribute__((address_space(3)))

typedef __attribute__((ext_vector_type(8))) short bf16x8;
typedef __attribute__((ext_vector_type(4))) float f32x4;
typedef __attribute__((ext_vector_type(4))) unsigned int u32x4;

__device__ __forceinline__ unsigned int cvt_pk_bf16(float lo, float hi) {
    unsigned int r;
    asm("v_cvt_pk_bf16_f32 %0, %1, %2" : "=v"(r) : "v"(lo), "v"(hi));
    return r;
}

// ---------------------------------------------------------------------------
// W precompute (fp32 -> bf16, slot-swizzled) + padded bucketCursor zeroing.
// ---------------------------------------------------------------------------
__global__ __launch_bounds__(256) void wconv_kernel(const float* __restrict__ W,
                                                    unsigned short* __restrict__ Wswz,
                                                    int* __restrict__ bucketCursor) {
    int i = blockIdx.x * 256 + threadIdx.x;   // 2048 threads total
    int r = i >> 4, s = i & 15;
    const float4* wp = reinterpret_cast<const float4*>(W + (size_t)r * D + s * 8);
    float4 v0 = wp[0], v1 = wp[1];
    uint2 a, b;
    a.x = cvt_pk_bf16(v0.x, v0.y); a.y = cvt_pk_bf16(v0.z, v0.w);
    b.x = cvt_pk_bf16(v1.x, v1.y); b.y = cvt_pk_bf16(v1.z, v1.w);
    int so = s ^ (r & 15);
    unsigned short* op = Wswz + (size_t)r * D + so * 8;
    *reinterpret_cast<uint2*>(op)     = a;
    *reinterpret_cast<uint2*>(op + 4) = b;
    for (int z = i; z < NB * CURSTRIDE; z += 2048) bucketCursor[z] = 0;
}

// ---------------------------------------------------------------------------
// FUSED gemm + scatter (r15/r16-identical).
// ---------------------------------------------------------------------------
__global__ __launch_bounds__(256) void gemm_scatter_kernel(const float* __restrict__ x,
                                                           const unsigned short* __restrict__ Wswz,
                                                           unsigned short* __restrict__ h,
                                                           const int* __restrict__ src,
                                                           const int* __restrict__ dst,
                                                           const float* __restrict__ vals,
                                                           int* __restrict__ bucketCursor,
                                                           uint2* __restrict__ ebuf) {
    __shared__ __align__(16) unsigned char smem[40960];
    const int tid = threadIdx.x;
    const int lane = tid & 63;
    const int w = tid >> 6;
    const int g = blockIdx.x;

    if (g < SC_BLOCKS) {
        // ================= SCATTER role =================
        uint2* s_rec        = reinterpret_cast<uint2*>(smem);                    // 25000 B
        int*   l_off        = reinterpret_cast<int*>(smem + 25000);              // 3128 B
        int*   l_cur        = reinterpret_cast<int*>(smem + 28128);              // 3128 B
        int*   l_cnt        = reinterpret_cast<int*>(smem + 31256);              // 3128 B
        int*   wtot         = reinterpret_cast<int*>(smem + 34384);              // 16 B
        unsigned short* s_b = reinterpret_cast<unsigned short*>(smem + 34400);   // 6250 B

        const int t = tid;
        const int cb = g * SC_CHUNK;

        for (int i = t; i < NB; i += 256) l_cnt[i] = 0;
        __syncthreads();

        int dreg[SC_IT];
#pragma unroll
        for (int i = 0; i < SC_IT; ++i) {
            int o = t + 256 * i;
            dreg[i] = (o < SC_CHUNK) ? dst[cb + o] : -1;
            if (dreg[i] >= 0) atomicAdd(&l_cnt[dreg[i] >> 7], 1);
        }
        __syncthreads();

        int c[4];
        int s = 0;
#pragma unroll
        for (int i = 0; i < 4; ++i) {
            int b = 4 * t + i;
            c[i] = (b < NB) ? l_cnt[b] : 0;
            s += c[i];
        }
        int incl = s;
#pragma unroll
        for (int off = 1; off < 64; off <<= 1) {
            int v = __shfl_up(incl, off);
            if (lane >= off) incl += v;
        }
        if (lane == 63) wtot[w] = incl;
        __syncthreads();
        int run = incl - s;
        for (int k = 0; k < 4; ++k) if (k < w) run += wtot[k];
#pragma unroll
        for (int i = 0; i < 4; ++i) {
            int b = 4 * t + i;
            if (b < NB) {
                l_cur[b] = run;
                int gbase = b * CAPB +
                    (c[i] ? atomicAdd(&bucketCursor[b * CURSTRIDE], c[i]) : 0);
                l_off[b] = gbase - run;
            }
            run += c[i];
        }
        __syncthreads();

#pragma unroll
        for (int i = 0; i < SC_IT; ++i) {
            int o = t + 256 * i;
            if (dreg[i] >= 0) {
                int dn = dreg[i];
                int b = dn >> 7;
                uint2 rec;
                rec.x = (unsigned int)src[cb + o] | ((unsigned int)(dn & 127) << 17);
                rec.y = __float_as_uint(vals[cb + o]);
                int lofs = atomicAdd(&l_cur[b], 1);
                s_rec[lofs] = rec;
                s_b[lofs] = (unsigned short)b;
            }
        }
        __syncthreads();

#pragma unroll
        for (int i = 0; i < SC_IT; ++i) {
            int j = t + 256 * i;
            if (j < SC_CHUNK) {
                int b = s_b[j];
                ebuf[l_off[b] + j] = s_rec[j];
            }
        }
    } else {
        // ================= GEMM role (BM=64, reg-A) =================
        unsigned char* lBbuf = smem;                                   // 32768 B
        const int rowBase = (g - SC_BLOCKS) * BM;

#pragma unroll
        for (int q = 0; q < 8; ++q) {
            const unsigned char* gp = reinterpret_cast<const unsigned char*>(Wswz)
                                      + (size_t)((w * 8 + q) * 1024 + lane * 16);
            unsigned char* lp = lBbuf + (w * 8 + q) * 1024;
            __builtin_amdgcn_global_load_lds((ASG const unsigned int*)(const void*)gp,
                                             (ASL unsigned int*)(void*)lp, 16, 0, 0);
        }

        const int l16 = lane & 15;
        const int arow = min(rowBase + w * 16 + l16, NN - 1);
        const float* xrow = x + (size_t)arow * D + (lane >> 4) * 8;

        bf16x8 afr[4];
#pragma unroll
        for (int kk = 0; kk < 4; ++kk) {
            float4 v0 = *reinterpret_cast<const float4*>(xrow + kk * 32);
            float4 v1 = *reinterpret_cast<const float4*>(xrow + kk * 32 + 4);
            u32x4 u;
            u[0] = cvt_pk_bf16(v0.x, v0.y);
            u[1] = cvt_pk_bf16(v0.z, v0.w);
            u[2] = cvt_pk_bf16(v1.x, v1.y);
            u[3] = cvt_pk_bf16(v1.z, v1.w);
            afr[kk] = __builtin_bit_cast(bf16x8, u);
        }
        __syncthreads();   // drains vmcnt (W DMA)

        const int kx16 = (lane >> 4) * 16;
        f32x4 acc[8];
#pragma unroll
        for (int j = 0; j < 8; ++j) acc[j] = (f32x4){0.f, 0.f, 0.f, 0.f};

        const int bxor = l16 << 4;
#pragma unroll
        for (int kk = 0; kk < 4; ++kk) {
            int kbyte = kk * 64 + kx16;
#pragma unroll
            for (int j = 0; j < 8; ++j) {
                int row = j * 16 + l16;
                bf16x8 b = *reinterpret_cast<const bf16x8*>(
                    lBbuf + row * 256 + (kbyte ^ bxor));
                acc[j] = __builtin_amdgcn_mfma_f32_16x16x32_bf16(afr[kk], b, acc[j], 0, 0, 0);
            }
        }
        __syncthreads();   // all waves done with lB -> reuse as transpose buffer

        const int lr0 = w * 16 + (lane >> 4) * 4;
#pragma unroll
        for (int j = 0; j < 8; ++j) {
            int col = j * 16 + l16;
            unsigned int d01 = cvt_pk_bf16(acc[j][0], acc[j][1]);
            unsigned int d23 = cvt_pk_bf16(acc[j][2], acc[j][3]);
            unsigned char* p0 = lBbuf + lr0 * TPAD + col * 2;
            *reinterpret_cast<unsigned short*>(p0)            = (unsigned short)d01;
            *reinterpret_cast<unsigned short*>(p0 + TPAD)     = (unsigned short)(d01 >> 16);
            *reinterpret_cast<unsigned short*>(p0 + 2 * TPAD) = (unsigned short)d23;
            *reinterpret_cast<unsigned short*>(p0 + 3 * TPAD) = (unsigned short)(d23 >> 16);
        }
        __syncthreads();

#pragma unroll
        for (int i = 0; i < 8; ++i) {
            int f = tid + 256 * i;
            int r = f >> 5, c = f & 31;
            if (rowBase + r < NN) {
                uint2 v = *reinterpret_cast<const uint2*>(lBbuf + r * TPAD + c * 8);
                *reinterpret_cast<uint2*>(reinterpret_cast<unsigned char*>(h)
                                          + (size_t)(rowBase + r) * 256 + c * 8) = v;
            }
        }
    }
}

// ---------------------------------------------------------------------------
// Pull: 256-thread block per quarter-bucket (r16 shape). NEW dual-edge
// consume: lane l reads 8 B (4 dims) of edge e+(l>>5) via ds_read_b64 --
// one read + one broadcast v-read + 4 fma per PAIR of edges; branch-hoisted
// segments between gate refills. Halves combined by shfl_xor(32) at the end.
// ---------------------------------------------------------------------------
__global__ __launch_bounds__(256) void pull_kernel(const unsigned short* __restrict__ h,
                                                   const int* __restrict__ bucketCursor,
                                                   const uint2* __restrict__ ebuf,
                                                   float* __restrict__ out) {
    __shared__ uint2 srec[CAP + 1];                          // 6152 B
    __shared__ int cnt[32];
    __shared__ int start[33];
    __shared__ int cur[32];
    __shared__ __align__(16) unsigned char hbuf[4 * 4096];   // 16 KB

    const int t = threadIdx.x;
    const int lane = t & 63;
    const int w = t >> 6;                // 4 waves
    const int bid = blockIdx.x;
    const int b = bid >> 2;
    const int quarter = bid & 3;
    const int nodeBase = b * 128 + quarter * 32;

    unsigned char* hbufW = hbuf + w * 4096;

    const int n = min(bucketCursor[b * CURSTRIDE], CAPB);
    const uint2* eb = ebuf + (size_t)b * CAPB;

    if (t < 32) cnt[t] = 0;
    __syncthreads();

    // pass 1: read records once into registers; histogram own-quarter dst
    uint2 rcache[10];
#pragma unroll
    for (int it = 0; it < 10; ++it) {
        int j = t + 256 * it;
        uint2 r = (j < n) ? eb[j] : (uint2){0xFFFFFFFFu, 0u};
        rcache[it] = r;
        if (j < n) {
            int dl = (int)((r.x >> 17) & 127);
            if ((dl >> 5) == quarter) atomicAdd(&cnt[dl & 31], 1);
        }
    }
    __syncthreads();

    // wave-0: 32-bin shuffle scan
    if (w == 0) {
        int c = (lane < 32) ? cnt[lane] : 0;
        int s = c;
        for (int off = 1; off < 32; off <<= 1) {
            int v = __shfl_up(s, off);
            if (lane >= off) s += v;
        }
        if (lane < 32) { start[lane] = s - c; cur[lane] = s - c; }
        if (lane == 31) start[32] = s;
    }
    __syncthreads();

    // pass 2: scatter own cached records into srec sorted by local dst
#pragma unroll
    for (int it = 0; it < 10; ++it) {
        int j = t + 256 * it;
        if (j < n) {
            uint2 rec = rcache[it];
            int dl = (int)((rec.x >> 17) & 127);
            if ((dl >> 5) == quarter) {
                int p = atomicAdd(&cur[dl & 31], 1);
                srec[p] = rec;
            }
        }
    }
    __syncthreads();

    // ---- dual-edge streamed accumulate: wave w owns nodes [w*8, w*8+8) ----
    const int wbeg = start[w * 8];
    const int wend = start[w * 8 + 8];
    const int lh  = lane >> 5;           // 0 = lower half, 1 = upper half
    const int l31 = lane & 31;
    int issued = 0;
    int consumed = 0;

    auto issue_group = [&]() {
        int gbase = wbeg + issued * 8;
#pragma unroll
        for (int q = 0; q < 2; ++q) {
            int idx = min(gbase + q * 4 + (lane >> 4), wend - 1);
            unsigned int rx = reinterpret_cast<const unsigned int*>(&srec[idx])[0];
            const unsigned char* gp = reinterpret_cast<const unsigned char*>(h)
                                      + (size_t)(rx & 0x1FFFFu) * 256 + (size_t)((lane & 15) * 16);
            unsigned char* lp = hbufW + (issued & 1) * 2048 + q * 1024;
            __builtin_amdgcn_global_load_lds((ASG const unsigned int*)(const void*)gp,
                                             (ASL unsigned int*)(void*)lp, 16, 0, 0);
        }
        issued++;
    };

    if (wend > wbeg) { issue_group(); issue_group(); }

    int gate = wbeg;
    const unsigned char* slotbase = hbufW;
    const unsigned int* srec_dw = reinterpret_cast<const unsigned int*>(srec);

    float4 acc4[8];
#pragma unroll
    for (int i = 0; i < 8; ++i) acc4[i] = (float4){0.f, 0.f, 0.f, 0.f};

#pragma unroll
    for (int i = 0; i < 8; ++i) {
        const int s1 = start[w * 8 + i + 1];
        int e = start[w * 8 + i];
        float4 a = acc4[i];
        while (e < s1) {
            if (e >= gate) {
                if (consumed) issue_group();
                asm volatile("s_waitcnt vmcnt(2)" ::: "memory");
                __builtin_amdgcn_sched_barrier(0);
                slotbase = hbufW + (consumed & 1) * 2048;
                consumed++;
                gate += 8;
            }
            const int lim = min(s1, gate);
            // pair loop (branch-free body): edges e (lower half) and e+1 (upper)
            for (; e + 1 < lim; e += 2) {
                int le = e - wbeg;
                uint2 hw2 = *reinterpret_cast<const uint2*>(
                    slotbase + ((le + lh) & 7) * 256 + l31 * 8);
                float v = __uint_as_float(srec_dw[(e + lh) * 2 + 1]);
                a.x = fmaf(v, __uint_as_float(hw2.x << 16),         a.x);
                a.y = fmaf(v, __uint_as_float(hw2.x & 0xFFFF0000u), a.y);
                a.z = fmaf(v, __uint_as_float(hw2.y << 16),         a.z);
                a.w = fmaf(v, __uint_as_float(hw2.y & 0xFFFF0000u), a.w);
            }
            if (e < lim) {   // solo tail edge: upper half contributes 0
                int le = e - wbeg;
                uint2 hw2 = *reinterpret_cast<const uint2*>(
                    slotbase + ((le + lh) & 7) * 256 + l31 * 8);
                float v = __uint_as_float(srec_dw[(e + lh) * 2 + 1]);
                if (lh) v = 0.f;
                a.x = fmaf(v, __uint_as_float(hw2.x << 16),         a.x);
                a.y = fmaf(v, __uint_as_float(hw2.x & 0xFFFF0000u), a.y);
                a.z = fmaf(v, __uint_as_float(hw2.y << 16),         a.z);
                a.w = fmaf(v, __uint_as_float(hw2.y & 0xFFFF0000u), a.w);
                ++e;
            }
        }
        acc4[i] = a;
    }
    __syncthreads();   // drains dangling DMA

    // epilogue: combine halves, exact GELU, float4 write (half (i&1) writes)
    const float is2 = 0.70710678118654752f;
#pragma unroll
    for (int i = 0; i < 8; ++i) {
        float4 o;
        o.x = acc4[i].x + __shfl_xor(acc4[i].x, 32);
        o.y = acc4[i].y + __shfl_xor(acc4[i].y, 32);
        o.z = acc4[i].z + __shfl_xor(acc4[i].z, 32);
        o.w = acc4[i].w + __shfl_xor(acc4[i].w, 32);
        if (lh == (i & 1)) {
            int node = nodeBase + w * 8 + i;
            if (node < NN) {
                o.x = 0.5f * o.x * (1.f + erff(o.x * is2));
                o.y = 0.5f * o.y * (1.f + erff(o.y * is2));
                o.z = 0.5f * o.z * (1.f + erff(o.z * is2));
                o.w = 0.5f * o.w * (1.f + erff(o.w * is2));
                *reinterpret_cast<float4*>(out + (size_t)node * D + l31 * 4) = o;
            }
        }
    }
}

extern "C" void kernel_launch(void* const* d_in, const int* in_sizes, int n_in,
                              void* d_out, int out_size, void* d_ws, size_t ws_size,
                              hipStream_t stream) {
    const float* x    = (const float*)d_in[0];
    const float* W    = (const float*)d_in[1];
    const float* vals = (const float*)d_in[2];
    const int*   src  = (const int*)d_in[3];
    const int*   dst  = (const int*)d_in[4];
    float* out = (float*)d_out;

    char* ws = (char*)d_ws;
    size_t off = 0;
    unsigned short* h    = (unsigned short*)(ws + off); off += (size_t)NN * D * 2;
    int* bucketCursor    = (int*)(ws + off);            off += (size_t)NB * CURSTRIDE * 4;
    off = (off + 15) & ~(size_t)15;
    unsigned short* Wswz = (unsigned short*)(ws + off); off += (size_t)D * D * 2;
    off = (off + 15) & ~(size_t)15;
    uint2* ebuf          = (uint2*)(ws + off);          off += (size_t)NB * CAPB * 8;

    wconv_kernel<<<8, 256, 0, stream>>>(W, Wswz, bucketCursor);
    gemm_scatter_kernel<<<GRID, 256, 0, stream>>>(
        x, Wswz, h, src, dst, vals, bucketCursor, ebuf);
    pull_kernel<<<NB * 4, 256, 0, stream>>>(h, bucketCursor, ebuf, out);
}

// Round 18
// 120.085 us; speedup vs baseline: 1.0876x; 1.0876x over previous
//
#include <hip/hip_runtime.h>
#include <math.h>

#define NN 100000
#define NE 1600000
#define D 128

#define NB 782                          // buckets of 128 dst-nodes
#define CAPB 2560                       // fixed ebuf capacity per bucket
#define CURSTRIDE 16                    // cursor padded to one 64B line per bucket
#define SC_BLOCKS 512                   // scatter role blocks
#define SC_CHUNK 3125                   // 512 x 3125 = 1.6M exactly
#define SC_IT 13                        // ceil(3125/256)
#define CAP 1408                        // pull sorted tile (half-bucket, mean 1023, +12 sigma)

#define BM 64                           // rows per gemm block
#define GM_BLOCKS 1563                  // ceil(NN/64)
#define GRID (SC_BLOCKS + GM_BLOCKS)    // 2075
#define TPAD 264                        // transpose-epilogue row stride (bytes)

#define ASG __attribute__((address_space(1)))
#define ASL __attribute__((address_space(3)))

typedef __attribute__((ext_vector_type(8))) short bf16x8;
typedef __attribute__((ext_vector_type(4))) float f32x4;
typedef __attribute__((ext_vector_type(4))) unsigned int u32x4;

__device__ __forceinline__ unsigned int cvt_pk_bf16(float lo, float hi) {
    unsigned int r;
    asm("v_cvt_pk_bf16_f32 %0, %1, %2" : "=v"(r) : "v"(lo), "v"(hi));
    return r;
}

// ---------------------------------------------------------------------------
// W precompute (fp32 -> bf16, slot-swizzled) + padded bucketCursor zeroing.
// ---------------------------------------------------------------------------
__global__ __launch_bounds__(256) void wconv_kernel(const float* __restrict__ W,
                                                    unsigned short* __restrict__ Wswz,
                                                    int* __restrict__ bucketCursor) {
    int i = blockIdx.x * 256 + threadIdx.x;   // 2048 threads total
    int r = i >> 4, s = i & 15;
    const float4* wp = reinterpret_cast<const float4*>(W + (size_t)r * D + s * 8);
    float4 v0 = wp[0], v1 = wp[1];
    uint2 a, b;
    a.x = cvt_pk_bf16(v0.x, v0.y); a.y = cvt_pk_bf16(v0.z, v0.w);
    b.x = cvt_pk_bf16(v1.x, v1.y); b.y = cvt_pk_bf16(v1.z, v1.w);
    int so = s ^ (r & 15);
    unsigned short* op = Wswz + (size_t)r * D + so * 8;
    *reinterpret_cast<uint2*>(op)     = a;
    *reinterpret_cast<uint2*>(op + 4) = b;
    for (int z = i; z < NB * CURSTRIDE; z += 2048) bucketCursor[z] = 0;
}

// ---------------------------------------------------------------------------
// FUSED gemm + scatter (r15-identical).
// ---------------------------------------------------------------------------
__global__ __launch_bounds__(256) void gemm_scatter_kernel(const float* __restrict__ x,
                                                           const unsigned short* __restrict__ Wswz,
                                                           unsigned short* __restrict__ h,
                                                           const int* __restrict__ src,
                                                           const int* __restrict__ dst,
                                                           const float* __restrict__ vals,
                                                           int* __restrict__ bucketCursor,
                                                           uint2* __restrict__ ebuf) {
    __shared__ __align__(16) unsigned char smem[40960];
    const int tid = threadIdx.x;
    const int lane = tid & 63;
    const int w = tid >> 6;
    const int g = blockIdx.x;

    if (g < SC_BLOCKS) {
        // ================= SCATTER role =================
        uint2* s_rec        = reinterpret_cast<uint2*>(smem);                    // 25000 B
        int*   l_off        = reinterpret_cast<int*>(smem + 25000);              // 3128 B
        int*   l_cur        = reinterpret_cast<int*>(smem + 28128);              // 3128 B
        int*   l_cnt        = reinterpret_cast<int*>(smem + 31256);              // 3128 B
        int*   wtot         = reinterpret_cast<int*>(smem + 34384);              // 16 B
        unsigned short* s_b = reinterpret_cast<unsigned short*>(smem + 34400);   // 6250 B

        const int t = tid;
        const int cb = g * SC_CHUNK;

        for (int i = t; i < NB; i += 256) l_cnt[i] = 0;
        __syncthreads();

        int dreg[SC_IT];
#pragma unroll
        for (int i = 0; i < SC_IT; ++i) {
            int o = t + 256 * i;
            dreg[i] = (o < SC_CHUNK) ? dst[cb + o] : -1;
            if (dreg[i] >= 0) atomicAdd(&l_cnt[dreg[i] >> 7], 1);
        }
        __syncthreads();

        int c[4];
        int s = 0;
#pragma unroll
        for (int i = 0; i < 4; ++i) {
            int b = 4 * t + i;
            c[i] = (b < NB) ? l_cnt[b] : 0;
            s += c[i];
        }
        int incl = s;
#pragma unroll
        for (int off = 1; off < 64; off <<= 1) {
            int v = __shfl_up(incl, off);
            if (lane >= off) incl += v;
        }
        if (lane == 63) wtot[w] = incl;
        __syncthreads();
        int run = incl - s;
        for (int k = 0; k < 4; ++k) if (k < w) run += wtot[k];
#pragma unroll
        for (int i = 0; i < 4; ++i) {
            int b = 4 * t + i;
            if (b < NB) {
                l_cur[b] = run;
                int gbase = b * CAPB +
                    (c[i] ? atomicAdd(&bucketCursor[b * CURSTRIDE], c[i]) : 0);
                l_off[b] = gbase - run;
            }
            run += c[i];
        }
        __syncthreads();

#pragma unroll
        for (int i = 0; i < SC_IT; ++i) {
            int o = t + 256 * i;
            if (dreg[i] >= 0) {
                int dn = dreg[i];
                int b = dn >> 7;
                uint2 rec;
                rec.x = (unsigned int)src[cb + o] | ((unsigned int)(dn & 127) << 17);
                rec.y = __float_as_uint(vals[cb + o]);
                int lofs = atomicAdd(&l_cur[b], 1);
                s_rec[lofs] = rec;
                s_b[lofs] = (unsigned short)b;
            }
        }
        __syncthreads();

#pragma unroll
        for (int i = 0; i < SC_IT; ++i) {
            int j = t + 256 * i;
            if (j < SC_CHUNK) {
                int b = s_b[j];
                ebuf[l_off[b] + j] = s_rec[j];
            }
        }
    } else {
        // ================= GEMM role (BM=64, reg-A) =================
        unsigned char* lBbuf = smem;                                   // 32768 B
        const int rowBase = (g - SC_BLOCKS) * BM;

#pragma unroll
        for (int q = 0; q < 8; ++q) {
            const unsigned char* gp = reinterpret_cast<const unsigned char*>(Wswz)
                                      + (size_t)((w * 8 + q) * 1024 + lane * 16);
            unsigned char* lp = lBbuf + (w * 8 + q) * 1024;
            __builtin_amdgcn_global_load_lds((ASG const unsigned int*)(const void*)gp,
                                             (ASL unsigned int*)(void*)lp, 16, 0, 0);
        }

        const int l16 = lane & 15;
        const int arow = min(rowBase + w * 16 + l16, NN - 1);
        const float* xrow = x + (size_t)arow * D + (lane >> 4) * 8;

        bf16x8 afr[4];
#pragma unroll
        for (int kk = 0; kk < 4; ++kk) {
            float4 v0 = *reinterpret_cast<const float4*>(xrow + kk * 32);
            float4 v1 = *reinterpret_cast<const float4*>(xrow + kk * 32 + 4);
            u32x4 u;
            u[0] = cvt_pk_bf16(v0.x, v0.y);
            u[1] = cvt_pk_bf16(v0.z, v0.w);
            u[2] = cvt_pk_bf16(v1.x, v1.y);
            u[3] = cvt_pk_bf16(v1.z, v1.w);
            afr[kk] = __builtin_bit_cast(bf16x8, u);
        }
        __syncthreads();   // drains vmcnt (W DMA)

        const int kx16 = (lane >> 4) * 16;
        f32x4 acc[8];
#pragma unroll
        for (int j = 0; j < 8; ++j) acc[j] = (f32x4){0.f, 0.f, 0.f, 0.f};

        const int bxor = l16 << 4;
#pragma unroll
        for (int kk = 0; kk < 4; ++kk) {
            int kbyte = kk * 64 + kx16;
#pragma unroll
            for (int j = 0; j < 8; ++j) {
                int row = j * 16 + l16;
                bf16x8 b = *reinterpret_cast<const bf16x8*>(
                    lBbuf + row * 256 + (kbyte ^ bxor));
                acc[j] = __builtin_amdgcn_mfma_f32_16x16x32_bf16(afr[kk], b, acc[j], 0, 0, 0);
            }
        }
        __syncthreads();   // all waves done with lB -> reuse as transpose buffer

        const int lr0 = w * 16 + (lane >> 4) * 4;
#pragma unroll
        for (int j = 0; j < 8; ++j) {
            int col = j * 16 + l16;
            unsigned int d01 = cvt_pk_bf16(acc[j][0], acc[j][1]);
            unsigned int d23 = cvt_pk_bf16(acc[j][2], acc[j][3]);
            unsigned char* p0 = lBbuf + lr0 * TPAD + col * 2;
            *reinterpret_cast<unsigned short*>(p0)            = (unsigned short)d01;
            *reinterpret_cast<unsigned short*>(p0 + TPAD)     = (unsigned short)(d01 >> 16);
            *reinterpret_cast<unsigned short*>(p0 + 2 * TPAD) = (unsigned short)d23;
            *reinterpret_cast<unsigned short*>(p0 + 3 * TPAD) = (unsigned short)(d23 >> 16);
        }
        __syncthreads();

#pragma unroll
        for (int i = 0; i < 8; ++i) {
            int f = tid + 256 * i;
            int r = f >> 5, c = f & 31;
            if (rowBase + r < NN) {
                uint2 v = *reinterpret_cast<const uint2*>(lBbuf + r * TPAD + c * 8);
                *reinterpret_cast<uint2*>(reinterpret_cast<unsigned char*>(h)
                                          + (size_t)(rowBase + r) * 256 + c * 8) = v;
            }
        }
    }
}

// ---------------------------------------------------------------------------
// Pull (r15 shape: 512 threads, half-bucket, 8 waves x 8 nodes). Consume is
// segment-hoisted unroll-2 (per-lane, uniform — no half-split): between gate
// refills all edges live in one known slot; tight pair loop with 2
// independent load+fma chains and one pointer walk.
// ---------------------------------------------------------------------------
__global__ __launch_bounds__(512) void pull_kernel(const unsigned short* __restrict__ h,
                                                   const int* __restrict__ bucketCursor,
                                                   const uint2* __restrict__ ebuf,
                                                   float* __restrict__ out) {
    __shared__ uint2 srec[CAP];                              // 11264 B
    __shared__ int cnt[64];
    __shared__ int start[65];
    __shared__ int cur[64];
    __shared__ __align__(16) unsigned char hbuf[8 * 4096];   // 32 KB

    const int t = threadIdx.x;
    const int lane = t & 63;
    const int w = t >> 6;                // 8 waves
    const int bid = blockIdx.x;
    const int b = bid >> 1;
    const int half = bid & 1;
    const int nodeBase = b * 128 + half * 64;

    unsigned char* hbufW = hbuf + w * 4096;

    float2 acc[8];
#pragma unroll
    for (int i = 0; i < 8; ++i) acc[i] = (float2){0.f, 0.f};

    const int n = min(bucketCursor[b * CURSTRIDE], CAPB);
    const uint2* eb = ebuf + (size_t)b * CAPB;

    if (t < 64) cnt[t] = 0;
    __syncthreads();

    // pass 1: read records once into registers; histogram own-half dst
    uint2 rcache[5];
#pragma unroll
    for (int it = 0; it < 5; ++it) {
        int j = t + 512 * it;
        uint2 r = (j < n) ? eb[j] : (uint2){0xFFFFFFFFu, 0u};
        rcache[it] = r;
        if (j < n) {
            int dl = (int)((r.x >> 17) & 127);
            if ((dl >> 6) == half) atomicAdd(&cnt[dl & 63], 1);
        }
    }
    __syncthreads();

    if (w == 0) {
        int c = cnt[lane];
        int s = c;
        for (int off = 1; off < 64; off <<= 1) {
            int v = __shfl_up(s, off);
            if (lane >= off) s += v;
        }
        start[lane] = s - c;
        cur[lane] = s - c;
        if (lane == 63) start[64] = s;
    }
    __syncthreads();

    // pass 2: scatter own cached records into srec sorted by local dst
#pragma unroll
    for (int it = 0; it < 5; ++it) {
        int j = t + 512 * it;
        if (j < n) {
            uint2 rec = rcache[it];
            int dl = (int)((rec.x >> 17) & 127);
            if ((dl >> 6) == half) {
                int p = atomicAdd(&cur[dl & 63], 1);
                srec[p] = rec;
            }
        }
    }
    __syncthreads();

    // ---- streamed accumulate: wave w owns nodes [w*8, w*8+8) ----
    const int wbeg = start[w * 8];
    const int wend = start[w * 8 + 8];
    int issued = 0;
    int consumed = 0;

    auto issue_group = [&]() {
        int gbase = wbeg + issued * 8;
#pragma unroll
        for (int q = 0; q < 2; ++q) {
            int idx = min(gbase + q * 4 + (lane >> 4), wend - 1);
            unsigned int rx = reinterpret_cast<const unsigned int*>(&srec[idx])[0];
            const unsigned char* gp = reinterpret_cast<const unsigned char*>(h)
                                      + (size_t)(rx & 0x1FFFFu) * 256 + (size_t)((lane & 15) * 16);
            unsigned char* lp = hbufW + (issued & 1) * 2048 + q * 1024;
            __builtin_amdgcn_global_load_lds((ASG const unsigned int*)(const void*)gp,
                                             (ASL unsigned int*)(void*)lp, 16, 0, 0);
        }
        issued++;
    };

    if (wend > wbeg) { issue_group(); issue_group(); }

    int gate = wbeg;
    const unsigned char* slotcur = hbufW;
    const unsigned int* srec_dw = reinterpret_cast<const unsigned int*>(srec);

#pragma unroll
    for (int i = 0; i < 8; ++i) {
        const int s1 = start[w * 8 + i + 1];
        int e = start[w * 8 + i];
        float2 a = acc[i];
        while (e < s1) {
            if (e >= gate) {
                if (consumed) issue_group();
                asm volatile("s_waitcnt vmcnt(2)" ::: "memory");
                __builtin_amdgcn_sched_barrier(0);
                slotcur = hbufW + (consumed & 1) * 2048;
                consumed++;
                gate += 8;
            }
            const int lim = min(s1, gate);
            const unsigned char* hp = slotcur + ((e - wbeg) & 7) * 256 + lane * 4;
            // pair loop: two independent load+fma chains, one pointer walk
            for (; e + 1 < lim; e += 2) {
                unsigned int h0 = *reinterpret_cast<const unsigned int*>(hp);
                unsigned int h1 = *reinterpret_cast<const unsigned int*>(hp + 256);
                float v0 = __uint_as_float(srec_dw[e * 2 + 1]);
                float v1 = __uint_as_float(srec_dw[e * 2 + 3]);
                a.x = fmaf(v0, __uint_as_float(h0 << 16),         a.x);
                a.y = fmaf(v0, __uint_as_float(h0 & 0xFFFF0000u), a.y);
                a.x = fmaf(v1, __uint_as_float(h1 << 16),         a.x);
                a.y = fmaf(v1, __uint_as_float(h1 & 0xFFFF0000u), a.y);
                hp += 512;
            }
            if (e < lim) {
                unsigned int h0 = *reinterpret_cast<const unsigned int*>(hp);
                float v0 = __uint_as_float(srec_dw[e * 2 + 1]);
                a.x = fmaf(v0, __uint_as_float(h0 << 16),         a.x);
                a.y = fmaf(v0, __uint_as_float(h0 & 0xFFFF0000u), a.y);
                ++e;
            }
        }
        acc[i] = a;
    }
    __syncthreads();   // drains dangling DMA

    // epilogue: exact GELU + coalesced write
    const float is2 = 0.70710678118654752f;
#pragma unroll
    for (int i = 0; i < 8; ++i) {
        int node = nodeBase + w * 8 + i;
        if (node < NN) {
            float a0 = acc[i].x, a1 = acc[i].y;
            a0 = 0.5f * a0 * (1.f + erff(a0 * is2));
            a1 = 0.5f * a1 * (1.f + erff(a1 * is2));
            float2 o; o.x = a0; o.y = a1;
            *reinterpret_cast<float2*>(out + (size_t)node * D + lane * 2) = o;
        }
    }
}

extern "C" void kernel_launch(void* const* d_in, const int* in_sizes, int n_in,
                              void* d_out, int out_size, void* d_ws, size_t ws_size,
                              hipStream_t stream) {
    const float* x    = (const float*)d_in[0];
    const float* W    = (const float*)d_in[1];
    const float* vals = (const float*)d_in[2];
    const int*   src  = (const int*)d_in[3];
    const int*   dst  = (const int*)d_in[4];
    float* out = (float*)d_out;

    char* ws = (char*)d_ws;
    size_t off = 0;
    unsigned short* h    = (unsigned short*)(ws + off); off += (size_t)NN * D * 2;
    int* bucketCursor    = (int*)(ws + off);            off += (size_t)NB * CURSTRIDE * 4;
    off = (off + 15) & ~(size_t)15;
    unsigned short* Wswz = (unsigned short*)(ws + off); off += (size_t)D * D * 2;
    off = (off + 15) & ~(size_t)15;
    uint2* ebuf          = (uint2*)(ws + off);          off += (size_t)NB * CAPB * 8;

    wconv_kernel<<<8, 256, 0, stream>>>(W, Wswz, bucketCursor);
    gemm_scatter_kernel<<<GRID, 256, 0, stream>>>(
        x, Wswz, h, src, dst, vals, bucketCursor, ebuf);
    pull_kernel<<<NB * 2, 512, 0, stream>>>(h, bucketCursor, ebuf, out);
}

// Round 21
// 119.983 us; speedup vs baseline: 1.0885x; 1.0009x over previous
//
#include <hip/hip_runtime.h>
#include <math.h>

#define NN 100000
#define NE 1600000
#define D 128

#define NB 782                          // buckets of 128 dst-nodes
#define CAPB 2560                       // fixed ebuf capacity per bucket
#define CURSTRIDE 16                    // cursor padded to one 64B line per bucket
#define SC_BLOCKS 512                   // scatter role blocks
#define SC_CHUNK 3125                   // 512 x 3125 = 1.6M exactly
#define SC_IT 13                        // ceil(3125/256)
#define CAP 1408                        // pull sorted tile (half-bucket, mean 1023, +12 sigma)

#define BM 64                           // rows per gemm block
#define GM_BLOCKS 1563                  // ceil(NN/64)
#define GRID (SC_BLOCKS + GM_BLOCKS)    // 2075
#define TPAD 264                        // transpose-epilogue row stride (bytes)

#define ASG __attribute__((address_space(1)))
#define ASL __attribute__((address_space(3)))

typedef __attribute__((ext_vector_type(8))) short bf16x8;
typedef __attribute__((ext_vector_type(4))) float f32x4;
typedef __attribute__((ext_vector_type(4))) unsigned int u32x4;

__device__ __forceinline__ unsigned int cvt_pk_bf16(float lo, float hi) {
    unsigned int r;
    asm("v_cvt_pk_bf16_f32 %0, %1, %2" : "=v"(r) : "v"(lo), "v"(hi));
    return r;
}

// Pack two f32 -> packed f16 pair (round toward zero), as a dword.
__device__ __forceinline__ unsigned int cvt_pk_f16(float lo, float hi) {
    auto p = __builtin_amdgcn_cvt_pkrtz(lo, hi);
    return __builtin_bit_cast(unsigned int, p);
}

// Single-instruction f16-half * f32 + f32 (VOP3P v_fma_mix_f32, gfx9+).
__device__ __forceinline__ void fma_f16lo(float& acc, unsigned int h, float v) {
    asm("v_fma_mix_f32 %0, %1, %2, %0 op_sel:[0,0,0] op_sel_hi:[1,0,0]"
        : "+v"(acc) : "v"(h), "v"(v));
}
__device__ __forceinline__ void fma_f16hi(float& acc, unsigned int h, float v) {
    asm("v_fma_mix_f32 %0, %1, %2, %0 op_sel:[1,0,0] op_sel_hi:[1,0,0]"
        : "+v"(acc) : "v"(h), "v"(v));
}

// ---------------------------------------------------------------------------
// W precompute (fp32 -> bf16, slot-swizzled) + padded bucketCursor zeroing.
// ---------------------------------------------------------------------------
__global__ __launch_bounds__(256) void wconv_kernel(const float* __restrict__ W,
                                                    unsigned short* __restrict__ Wswz,
                                                    int* __restrict__ bucketCursor) {
    int i = blockIdx.x * 256 + threadIdx.x;   // 2048 threads total
    int r = i >> 4, s = i & 15;
    const float4* wp = reinterpret_cast<const float4*>(W + (size_t)r * D + s * 8);
    float4 v0 = wp[0], v1 = wp[1];
    uint2 a, b;
    a.x = cvt_pk_bf16(v0.x, v0.y); a.y = cvt_pk_bf16(v0.z, v0.w);
    b.x = cvt_pk_bf16(v1.x, v1.y); b.y = cvt_pk_bf16(v1.z, v1.w);
    int so = s ^ (r & 15);
    unsigned short* op = Wswz + (size_t)r * D + so * 8;
    *reinterpret_cast<uint2*>(op)     = a;
    *reinterpret_cast<uint2*>(op + 4) = b;
    for (int z = i; z < NB * CURSTRIDE; z += 2048) bucketCursor[z] = 0;
}

// ---------------------------------------------------------------------------
// FUSED gemm + scatter (r18 structure; gemm epilogue now packs h as f16).
// ---------------------------------------------------------------------------
__global__ __launch_bounds__(256) void gemm_scatter_kernel(const float* __restrict__ x,
                                                           const unsigned short* __restrict__ Wswz,
                                                           unsigned short* __restrict__ h,
                                                           const int* __restrict__ src,
                                                           const int* __restrict__ dst,
                                                           const float* __restrict__ vals,
                                                           int* __restrict__ bucketCursor,
                                                           uint2* __restrict__ ebuf) {
    __shared__ __align__(16) unsigned char smem[40960];
    const int tid = threadIdx.x;
    const int lane = tid & 63;
    const int w = tid >> 6;
    const int g = blockIdx.x;

    if (g < SC_BLOCKS) {
        // ================= SCATTER role =================
        uint2* s_rec        = reinterpret_cast<uint2*>(smem);                    // 25000 B
        int*   l_off        = reinterpret_cast<int*>(smem + 25000);              // 3128 B
        int*   l_cur        = reinterpret_cast<int*>(smem + 28128);              // 3128 B
        int*   l_cnt        = reinterpret_cast<int*>(smem + 31256);              // 3128 B
        int*   wtot         = reinterpret_cast<int*>(smem + 34384);              // 16 B
        unsigned short* s_b = reinterpret_cast<unsigned short*>(smem + 34400);   // 6250 B

        const int t = tid;
        const int cb = g * SC_CHUNK;

        for (int i = t; i < NB; i += 256) l_cnt[i] = 0;
        __syncthreads();

        int dreg[SC_IT];
#pragma unroll
        for (int i = 0; i < SC_IT; ++i) {
            int o = t + 256 * i;
            dreg[i] = (o < SC_CHUNK) ? dst[cb + o] : -1;
            if (dreg[i] >= 0) atomicAdd(&l_cnt[dreg[i] >> 7], 1);
        }
        __syncthreads();

        int c[4];
        int s = 0;
#pragma unroll
        for (int i = 0; i < 4; ++i) {
            int b = 4 * t + i;
            c[i] = (b < NB) ? l_cnt[b] : 0;
            s += c[i];
        }
        int incl = s;
#pragma unroll
        for (int off = 1; off < 64; off <<= 1) {
            int v = __shfl_up(incl, off);
            if (lane >= off) incl += v;
        }
        if (lane == 63) wtot[w] = incl;
        __syncthreads();
        int run = incl - s;
        for (int k = 0; k < 4; ++k) if (k < w) run += wtot[k];
#pragma unroll
        for (int i = 0; i < 4; ++i) {
            int b = 4 * t + i;
            if (b < NB) {
                l_cur[b] = run;
                int gbase = b * CAPB +
                    (c[i] ? atomicAdd(&bucketCursor[b * CURSTRIDE], c[i]) : 0);
                l_off[b] = gbase - run;
            }
            run += c[i];
        }
        __syncthreads();

#pragma unroll
        for (int i = 0; i < SC_IT; ++i) {
            int o = t + 256 * i;
            if (dreg[i] >= 0) {
                int dn = dreg[i];
                int b = dn >> 7;
                uint2 rec;
                rec.x = (unsigned int)src[cb + o] | ((unsigned int)(dn & 127) << 17);
                rec.y = __float_as_uint(vals[cb + o]);
                int lofs = atomicAdd(&l_cur[b], 1);
                s_rec[lofs] = rec;
                s_b[lofs] = (unsigned short)b;
            }
        }
        __syncthreads();

#pragma unroll
        for (int i = 0; i < SC_IT; ++i) {
            int j = t + 256 * i;
            if (j < SC_CHUNK) {
                int b = s_b[j];
                ebuf[l_off[b] + j] = s_rec[j];
            }
        }
    } else {
        // ================= GEMM role (BM=64, reg-A) =================
        unsigned char* lBbuf = smem;                                   // 32768 B
        const int rowBase = (g - SC_BLOCKS) * BM;

#pragma unroll
        for (int q = 0; q < 8; ++q) {
            const unsigned char* gp = reinterpret_cast<const unsigned char*>(Wswz)
                                      + (size_t)((w * 8 + q) * 1024 + lane * 16);
            unsigned char* lp = lBbuf + (w * 8 + q) * 1024;
            __builtin_amdgcn_global_load_lds((ASG const unsigned int*)(const void*)gp,
                                             (ASL unsigned int*)(void*)lp, 16, 0, 0);
        }

        const int l16 = lane & 15;
        const int arow = min(rowBase + w * 16 + l16, NN - 1);
        const float* xrow = x + (size_t)arow * D + (lane >> 4) * 8;

        bf16x8 afr[4];
#pragma unroll
        for (int kk = 0; kk < 4; ++kk) {
            float4 v0 = *reinterpret_cast<const float4*>(xrow + kk * 32);
            float4 v1 = *reinterpret_cast<const float4*>(xrow + kk * 32 + 4);
            u32x4 u;
            u[0] = cvt_pk_bf16(v0.x, v0.y);
            u[1] = cvt_pk_bf16(v0.z, v0.w);
            u[2] = cvt_pk_bf16(v1.x, v1.y);
            u[3] = cvt_pk_bf16(v1.z, v1.w);
            afr[kk] = __builtin_bit_cast(bf16x8, u);
        }
        __syncthreads();   // drains vmcnt (W DMA)

        const int kx16 = (lane >> 4) * 16;
        f32x4 acc[8];
#pragma unroll
        for (int j = 0; j < 8; ++j) acc[j] = (f32x4){0.f, 0.f, 0.f, 0.f};

        const int bxor = l16 << 4;
#pragma unroll
        for (int kk = 0; kk < 4; ++kk) {
            int kbyte = kk * 64 + kx16;
#pragma unroll
            for (int j = 0; j < 8; ++j) {
                int row = j * 16 + l16;
                bf16x8 b = *reinterpret_cast<const bf16x8*>(
                    lBbuf + row * 256 + (kbyte ^ bxor));
                acc[j] = __builtin_amdgcn_mfma_f32_16x16x32_bf16(afr[kk], b, acc[j], 0, 0, 0);
            }
        }
        __syncthreads();   // all waves done with lB -> reuse as transpose buffer

        // Transpose epilogue (h now packed f16): layout/stores unchanged.
        const int lr0 = w * 16 + (lane >> 4) * 4;
#pragma unroll
        for (int j = 0; j < 8; ++j) {
            int col = j * 16 + l16;
            unsigned int d01 = cvt_pk_f16(acc[j][0], acc[j][1]);
            unsigned int d23 = cvt_pk_f16(acc[j][2], acc[j][3]);
            unsigned char* p0 = lBbuf + lr0 * TPAD + col * 2;
            *reinterpret_cast<unsigned short*>(p0)            = (unsigned short)d01;
            *reinterpret_cast<unsigned short*>(p0 + TPAD)     = (unsigned short)(d01 >> 16);
            *reinterpret_cast<unsigned short*>(p0 + 2 * TPAD) = (unsigned short)d23;
            *reinterpret_cast<unsigned short*>(p0 + 3 * TPAD) = (unsigned short)(d23 >> 16);
        }
        __syncthreads();

#pragma unroll
        for (int i = 0; i < 8; ++i) {
            int f = tid + 256 * i;
            int r = f >> 5, c = f & 31;
            if (rowBase + r < NN) {
                uint2 v = *reinterpret_cast<const uint2*>(lBbuf + r * TPAD + c * 8);
                *reinterpret_cast<uint2*>(reinterpret_cast<unsigned char*>(h)
                                          + (size_t)(rowBase + r) * 256 + c * 8) = v;
            }
        }
    }
}

// ---------------------------------------------------------------------------
// Pull (r18 shape). Consume uses v_fma_mix_f32 on f16-packed h — 1 instr per
// half-FMA instead of unpack+fma; pair body 13-14 -> ~9 issues.
// ---------------------------------------------------------------------------
__global__ __launch_bounds__(512) void pull_kernel(const unsigned short* __restrict__ h,
                                                   const int* __restrict__ bucketCursor,
                                                   const uint2* __restrict__ ebuf,
                                                   float* __restrict__ out) {
    __shared__ uint2 srec[CAP];                              // 11264 B
    __shared__ int cnt[64];
    __shared__ int start[65];
    __shared__ int cur[64];
    __shared__ __align__(16) unsigned char hbuf[8 * 4096];   // 32 KB

    const int t = threadIdx.x;
    const int lane = t & 63;
    const int w = t >> 6;                // 8 waves
    const int bid = blockIdx.x;
    const int b = bid >> 1;
    const int half = bid & 1;
    const int nodeBase = b * 128 + half * 64;

    unsigned char* hbufW = hbuf + w * 4096;

    float2 acc[8];
#pragma unroll
    for (int i = 0; i < 8; ++i) acc[i] = (float2){0.f, 0.f};

    const int n = min(bucketCursor[b * CURSTRIDE], CAPB);
    const uint2* eb = ebuf + (size_t)b * CAPB;

    if (t < 64) cnt[t] = 0;
    __syncthreads();

    // pass 1: read records once into registers; histogram own-half dst
    uint2 rcache[5];
#pragma unroll
    for (int it = 0; it < 5; ++it) {
        int j = t + 512 * it;
        uint2 r = (j < n) ? eb[j] : (uint2){0xFFFFFFFFu, 0u};
        rcache[it] = r;
        if (j < n) {
            int dl = (int)((r.x >> 17) & 127);
            if ((dl >> 6) == half) atomicAdd(&cnt[dl & 63], 1);
        }
    }
    __syncthreads();

    if (w == 0) {
        int c = cnt[lane];
        int s = c;
        for (int off = 1; off < 64; off <<= 1) {
            int v = __shfl_up(s, off);
            if (lane >= off) s += v;
        }
        start[lane] = s - c;
        cur[lane] = s - c;
        if (lane == 63) start[64] = s;
    }
    __syncthreads();

    // pass 2: scatter own cached records into srec sorted by local dst
#pragma unroll
    for (int it = 0; it < 5; ++it) {
        int j = t + 512 * it;
        if (j < n) {
            uint2 rec = rcache[it];
            int dl = (int)((rec.x >> 17) & 127);
            if ((dl >> 6) == half) {
                int p = atomicAdd(&cur[dl & 63], 1);
                srec[p] = rec;
            }
        }
    }
    __syncthreads();

    // ---- streamed accumulate: wave w owns nodes [w*8, w*8+8) ----
    const int wbeg = start[w * 8];
    const int wend = start[w * 8 + 8];
    int issued = 0;
    int consumed = 0;

    auto issue_group = [&]() {
        int gbase = wbeg + issued * 8;
#pragma unroll
        for (int q = 0; q < 2; ++q) {
            int idx = min(gbase + q * 4 + (lane >> 4), wend - 1);
            unsigned int rx = reinterpret_cast<const unsigned int*>(&srec[idx])[0];
            const unsigned char* gp = reinterpret_cast<const unsigned char*>(h)
                                      + (size_t)(rx & 0x1FFFFu) * 256 + (size_t)((lane & 15) * 16);
            unsigned char* lp = hbufW + (issued & 1) * 2048 + q * 1024;
            __builtin_amdgcn_global_load_lds((ASG const unsigned int*)(const void*)gp,
                                             (ASL unsigned int*)(void*)lp, 16, 0, 0);
        }
        issued++;
    };

    if (wend > wbeg) { issue_group(); issue_group(); }

    int gate = wbeg;
    const unsigned char* slotcur = hbufW;
    const unsigned int* srec_dw = reinterpret_cast<const unsigned int*>(srec);

#pragma unroll
    for (int i = 0; i < 8; ++i) {
        const int s1 = start[w * 8 + i + 1];
        int e = start[w * 8 + i];
        float2 a = acc[i];
        while (e < s1) {
            if (e >= gate) {
                if (consumed) issue_group();
                asm volatile("s_waitcnt vmcnt(2)" ::: "memory");
                __builtin_amdgcn_sched_barrier(0);
                slotcur = hbufW + (consumed & 1) * 2048;
                consumed++;
                gate += 8;
            }
            const int lim = min(s1, gate);
            const unsigned char* hp = slotcur + ((e - wbeg) & 7) * 256 + lane * 4;
            // pair loop: two independent load+fma_mix chains, one pointer walk
            for (; e + 1 < lim; e += 2) {
                unsigned int h0 = *reinterpret_cast<const unsigned int*>(hp);
                unsigned int h1 = *reinterpret_cast<const unsigned int*>(hp + 256);
                float v0 = __uint_as_float(srec_dw[e * 2 + 1]);
                float v1 = __uint_as_float(srec_dw[e * 2 + 3]);
                fma_f16lo(a.x, h0, v0);
                fma_f16hi(a.y, h0, v0);
                fma_f16lo(a.x, h1, v1);
                fma_f16hi(a.y, h1, v1);
                hp += 512;
            }
            if (e < lim) {
                unsigned int h0 = *reinterpret_cast<const unsigned int*>(hp);
                float v0 = __uint_as_float(srec_dw[e * 2 + 1]);
                fma_f16lo(a.x, h0, v0);
                fma_f16hi(a.y, h0, v0);
                ++e;
            }
        }
        acc[i] = a;
    }
    __syncthreads();   // drains dangling DMA

    // epilogue: exact GELU + coalesced write
    const float is2 = 0.70710678118654752f;
#pragma unroll
    for (int i = 0; i < 8; ++i) {
        int node = nodeBase + w * 8 + i;
        if (node < NN) {
            float a0 = acc[i].x, a1 = acc[i].y;
            a0 = 0.5f * a0 * (1.f + erff(a0 * is2));
            a1 = 0.5f * a1 * (1.f + erff(a1 * is2));
            float2 o; o.x = a0; o.y = a1;
            *reinterpret_cast<float2*>(out + (size_t)node * D + lane * 2) = o;
        }
    }
}

extern "C" void kernel_launch(void* const* d_in, const int* in_sizes, int n_in,
                              void* d_out, int out_size, void* d_ws, size_t ws_size,
                              hipStream_t stream) {
    const float* x    = (const float*)d_in[0];
    const float* W    = (const float*)d_in[1];
    const float* vals = (const float*)d_in[2];
    const int*   src  = (const int*)d_in[3];
    const int*   dst  = (const int*)d_in[4];
    float* out = (float*)d_out;

    char* ws = (char*)d_ws;
    size_t off = 0;
    unsigned short* h    = (unsigned short*)(ws + off); off += (size_t)NN * D * 2;
    int* bucketCursor    = (int*)(ws + off);            off += (size_t)NB * CURSTRIDE * 4;
    off = (off + 15) & ~(size_t)15;
    unsigned short* Wswz = (unsigned short*)(ws + off); off += (size_t)D * D * 2;
    off = (off + 15) & ~(size_t)15;
    uint2* ebuf          = (uint2*)(ws + off);          off += (size_t)NB * CAPB * 8;

    wconv_kernel<<<8, 256, 0, stream>>>(W, Wswz, bucketCursor);
    gemm_scatter_kernel<<<GRID, 256, 0, stream>>>(
        x, Wswz, h, src, dst, vals, bucketCursor, ebuf);
    pull_kernel<<<NB * 2, 512, 0, stream>>>(h, bucketCursor, ebuf, out);
}